// Round 3
// baseline (249.671 us; speedup 1.0000x reference)
//
#include <hip/hip_runtime.h>
#include <hip/hip_bf16.h>

#define L    112
#define IMG  224
#define KS   7
#define CIN  3
#define COUT 64
#define BATCH 32
#define PAD  12
#define NPOS (BATCH * L * L)          // 401408
#define PLANE (L * L)                 // 12544
#define NTOT (NPOS * COUT)            // 25690112
#define EPS  1e-5f
#define KPAD 160                      // 147 rounded up to 32
#define NGIDX (PLANE * KPAD)          // 2006560

typedef short bf16x8 __attribute__((ext_vector_type(8)));
typedef float f32x4  __attribute__((ext_vector_type(4)));

__device__ __forceinline__ short f2bf(float v) {
    __hip_bfloat16 h = __float2bfloat16(v);   // RNE
    return *reinterpret_cast<short*>(&h);
}

// ---------------------------------------------------------------------------
// Prep A: Wt[o][k] bf16, k = c*49 + q*7 + p -> w[o][c][p][q]; zero for k>=147.
// ---------------------------------------------------------------------------
__global__ __launch_bounds__(256) void prep_weights(
    const float* __restrict__ w, unsigned short* __restrict__ wt)
{
    const int idx = blockIdx.x * 256 + threadIdx.x;   // < COUT*KPAD = 10240
    const int o = idx / KPAD;
    const int k = idx - o * KPAD;
    float v = 0.f;
    if (k < CIN * KS * KS) {
        const int c = (k >= 98) ? 2 : (k >= 49 ? 1 : 0);
        const int r = k - c * 49;
        const int q = (r * 37) >> 8;          // floor(r/7) for r<49
        const int p = r - q * 7;
        v = w[o * (CIN * KS * KS) + c * (KS * KS) + p * KS + q];
    }
    wt[idx] = (unsigned short)f2bf(v);
}

// ---------------------------------------------------------------------------
// Prep B: gather-offset table gidx[ij][k] (element offset into one batch
// image x[b], or -1 for padding). Batch-independent, L2-resident (8 MB).
// k>=147 -> -1 (value irrelevant: wt rows are zero there).
// ---------------------------------------------------------------------------
__global__ __launch_bounds__(256) void prep_gidx(
    const int* __restrict__ locs_i, const int* __restrict__ locs_j,
    int* __restrict__ gidx)
{
    const int idx = blockIdx.x * 256 + threadIdx.x;
    if (idx >= NGIDX) return;
    const int ij = idx / KPAD;
    const int k  = idx - ij * KPAD;
    int off = -1;
    if (k < CIN * KS * KS) {
        const int c = (k >= 98) ? 2 : (k >= 49 ? 1 : 0);
        const int r = k - c * 49;
        const int q = (r * 37) >> 8;
        const int p = r - q * 7;
        const int row  = locs_i[ij * KS + q] - PAD;
        const int colj = locs_j[ij * KS + p] - PAD;
        if ((unsigned)row < (unsigned)IMG && (unsigned)colj < (unsigned)IMG)
            off = c * (IMG * IMG) + row * IMG + colj;
    }
    gidx[idx] = off;
}

// ---------------------------------------------------------------------------
// Conv via MFMA. One wave = 16 consecutive positions x 64 channels.
// B-frag lane l: col = l&15 (position), k = ks*32 + 8*(l>>4) + e
//   -> offsets from gidx (2x dwordx4 per ks), then scattered x dword loads.
// A-frag lane l: row = l&15 (channel), same k -> b128 loads from Wt (L1-hot).
// C/D lane l: col = l&15 (position), row = (l>>4)*4+reg (channel).
// ---------------------------------------------------------------------------
__global__ __launch_bounds__(256) void foveal_conv_mfma(
    const float* __restrict__ x, const unsigned short* __restrict__ wt,
    const int* __restrict__ gidx, float* __restrict__ out)
{
    const int lane = threadIdx.x & 63;
    const int wid  = threadIdx.x >> 6;
    const int tile = blockIdx.x * 4 + wid;        // 25088 tiles of 16 positions
    const int posbase = tile * 16;
    const int b = posbase / PLANE;                // PLANE % 16 == 0
    const int ijbase = posbase - b * PLANE;
    const int col = lane & 15;
    const int kb  = (lane >> 4) * 8;

    const int* gp = gidx + (ijbase + col) * KPAD + kb;
    const float* xb = x + (size_t)b * (CIN * IMG * IMG);

    // 1) offset loads: 10x dwordx4, contiguous per lane
    int4 off[5][2];
#pragma unroll
    for (int ks = 0; ks < 5; ++ks) {
        off[ks][0] = *reinterpret_cast<const int4*>(gp + ks * 32);
        off[ks][1] = *reinterpret_cast<const int4*>(gp + ks * 32 + 4);
    }

    // 2) 40 independent scattered x loads + pad-select + bf16 pack
    bf16x8 bfrag[5];
#pragma unroll
    for (int ks = 0; ks < 5; ++ks) {
        const int o[8] = { off[ks][0].x, off[ks][0].y, off[ks][0].z, off[ks][0].w,
                           off[ks][1].x, off[ks][1].y, off[ks][1].z, off[ks][1].w };
        float v[8];
#pragma unroll
        for (int e = 0; e < 8; ++e) v[e] = xb[max(o[e], 0)];
#pragma unroll
        for (int e = 0; e < 8; ++e) {
            v[e] = (o[e] < 0) ? 0.5f : v[e];
            bfrag[ks][e] = f2bf(v[e]);
        }
    }

    // 3) MFMA with weight fragments loaded per k-step (L1-resident, 20 KB)
    f32x4 acc[4];
#pragma unroll
    for (int ct = 0; ct < 4; ++ct) acc[ct] = (f32x4){0.f, 0.f, 0.f, 0.f};

#pragma unroll
    for (int ks = 0; ks < 5; ++ks) {
        bf16x8 afrag[4];
#pragma unroll
        for (int ct = 0; ct < 4; ++ct)
            afrag[ct] = *reinterpret_cast<const bf16x8*>(
                wt + (ct * 16 + col) * KPAD + ks * 32 + kb);
#pragma unroll
        for (int ct = 0; ct < 4; ++ct)
            acc[ct] = __builtin_amdgcn_mfma_f32_16x16x32_bf16(
                afrag[ct], bfrag[ks], acc[ct], 0, 0, 0);
    }

    // 4) store: 16-lane groups write 16 consecutive ij per channel
#pragma unroll
    for (int ct = 0; ct < 4; ++ct) {
#pragma unroll
        for (int r = 0; r < 4; ++r) {
            const int ch = ct * 16 + (lane >> 4) * 4 + r;
            out[((size_t)b * COUT + ch) * PLANE + ijbase + col] = acc[ct][r];
        }
    }
}

// ---------------------------------------------------------------------------
// Pass 2a: per-channel sum / sumsq, float4 reads. One block per (b,o) plane.
// ---------------------------------------------------------------------------
__global__ __launch_bounds__(256) void reduce_stats(
    const float4* __restrict__ out, float* __restrict__ ws)
{
    const int plane = blockIdx.x;           // b*COUT + o
    const int o = plane & (COUT - 1);
    const float4* p = out + (size_t)plane * (PLANE / 4);

    float s = 0.f, sq = 0.f;
    for (int t = threadIdx.x; t < PLANE / 4; t += 256) {
        const float4 v = p[t];
        s  += v.x + v.y + v.z + v.w;
        sq += v.x * v.x + v.y * v.y + v.z * v.z + v.w * v.w;
    }
#pragma unroll
    for (int off = 32; off > 0; off >>= 1) {
        s  += __shfl_down(s,  off);
        sq += __shfl_down(sq, off);
    }
    __shared__ float ls[4], lsq[4];
    const int wid = threadIdx.x >> 6;
    if ((threadIdx.x & 63) == 0) { ls[wid] = s; lsq[wid] = sq; }
    __syncthreads();
    if (threadIdx.x == 0) {
        s  = ls[0] + ls[1] + ls[2] + ls[3];
        sq = lsq[0] + lsq[1] + lsq[2] + lsq[3];
        atomicAdd(&ws[o], s);
        atomicAdd(&ws[COUT + o], sq);
    }
}

__global__ __launch_bounds__(64) void fold_stats(
    float* __restrict__ ws, const float* __restrict__ gamma,
    const float* __restrict__ beta)
{
    const int o = threadIdx.x;
    const float n = (float)NPOS;
    const float mean = ws[o] / n;
    float var = ws[COUT + o] / n - mean * mean;
    var = fmaxf(var, 0.f);
    const float sc = gamma[o] * rsqrtf(var + EPS);
    ws[2 * COUT + o] = sc;
    ws[3 * COUT + o] = beta[o] - mean * sc;
}

__global__ __launch_bounds__(256) void norm_relu(
    float4* __restrict__ out, const float* __restrict__ ws)
{
    const int idx = blockIdx.x * 256 + threadIdx.x;   // < NTOT/4 (exact grid)
    const int o = (idx / (PLANE / 4)) & (COUT - 1);
    const float sc = ws[2 * COUT + o];
    const float sh = ws[3 * COUT + o];
    float4 v = out[idx];
    v.x = fmaxf(fmaf(v.x, sc, sh), 0.f);
    v.y = fmaxf(fmaf(v.y, sc, sh), 0.f);
    v.z = fmaxf(fmaf(v.z, sc, sh), 0.f);
    v.w = fmaxf(fmaf(v.w, sc, sh), 0.f);
    out[idx] = v;
}

// ---------------------------------------------------------------------------
extern "C" void kernel_launch(void* const* d_in, const int* in_sizes, int n_in,
                              void* d_out, int out_size, void* d_ws, size_t ws_size,
                              hipStream_t stream)
{
    const float* x      = (const float*)d_in[0];
    const float* conv_w = (const float*)d_in[1];
    const float* gamma  = (const float*)d_in[2];
    const float* beta   = (const float*)d_in[3];
    const int*   locs_i = (const int*)d_in[4];
    const int*   locs_j = (const int*)d_in[5];
    float* out = (float*)d_out;
    float* ws  = (float*)d_ws;
    unsigned short* wt = (unsigned short*)((char*)d_ws + 1024);       // 20480 B
    int* gidx = (int*)((char*)d_ws + 1024 + 20480);                   // 8 MB

    hipMemsetAsync(d_ws, 0, 1024, stream);  // zero stats area

    prep_weights<<<(COUT * KPAD) / 256, 256, 0, stream>>>(conv_w, wt);
    prep_gidx<<<(NGIDX + 255) / 256, 256, 0, stream>>>(locs_i, locs_j, gidx);
    foveal_conv_mfma<<<NPOS / 64, 256, 0, stream>>>(x, wt, gidx, out);
    reduce_stats<<<BATCH * COUT, 256, 0, stream>>>((const float4*)out, ws);
    fold_stats<<<1, 64, 0, stream>>>(ws, gamma, beta);
    norm_relu<<<NTOT / 4 / 256, 256, 0, stream>>>((float4*)out, ws);
}

// Round 4
// 225.643 us; speedup vs baseline: 1.1065x; 1.1065x over previous
//
#include <hip/hip_runtime.h>
#include <hip/hip_bf16.h>

#define L    112
#define IMG  224
#define KS   7
#define CIN  3
#define COUT 64
#define BATCH 32
#define PAD  12
#define NPOS (BATCH * L * L)          // 401408
#define PLANE (L * L)                 // 12544
#define NTOT (NPOS * COUT)            // 25690112
#define EPS  1e-5f
#define KPAD 160                      // 147 rounded up to 32
#define NGIDX (PLANE * KPAD)          // 2007040
#define NTILE (PLANE / 16)            // 784 position-tiles per batch
#define NWG   (NTILE * 8)             // 6272 conv blocks

typedef short bf16x8 __attribute__((ext_vector_type(8)));
typedef float f32x4  __attribute__((ext_vector_type(4)));

__device__ __forceinline__ short f2bf(float v) {
    __hip_bfloat16 h = __float2bfloat16(v);   // RNE
    return *reinterpret_cast<short*>(&h);
}

// hw slot -> logical k permutation (shared by weights, gidx, and implicitly
// the MFMA contraction): hw = ks*32 + kbi*8 + e  maps to
// k_log = ks*32 + e*4 + kbi. For fixed e, the 4 lane-groups (kbi) then read
// 4 ADJACENT taps -> coalesced x gathers.
__device__ __forceinline__ int hw_to_klog(int hw) {
    const int ks  = hw >> 5;
    const int r32 = hw & 31;
    const int kbi = r32 >> 3;
    const int e   = r32 & 7;
    return ks * 32 + e * 4 + kbi;
}

// ---------------------------------------------------------------------------
// Prep A: Wt[o][hw] bf16 with permuted k; k_log = c*49 + q*7 + p -> w[o][c][p][q].
// ---------------------------------------------------------------------------
__global__ __launch_bounds__(256) void prep_weights(
    const float* __restrict__ w, unsigned short* __restrict__ wt)
{
    const int idx = blockIdx.x * 256 + threadIdx.x;   // < COUT*KPAD = 10240
    const int o  = idx / KPAD;
    const int hw = idx - o * KPAD;
    const int k  = hw_to_klog(hw);
    float v = 0.f;
    if (k < CIN * KS * KS) {
        const int c = (k >= 98) ? 2 : (k >= 49 ? 1 : 0);
        const int r = k - c * 49;
        const int q = (r * 37) >> 8;          // floor(r/7) for r<49
        const int p = r - q * 7;
        v = w[o * (CIN * KS * KS) + c * (KS * KS) + p * KS + q];
    }
    wt[idx] = (unsigned short)f2bf(v);
}

// ---------------------------------------------------------------------------
// Prep B: gidx[ij][hw] = element offset into one batch image (or -1 = pad),
// permuted identically to the weights.
// ---------------------------------------------------------------------------
__global__ __launch_bounds__(256) void prep_gidx(
    const int* __restrict__ locs_i, const int* __restrict__ locs_j,
    int* __restrict__ gidx)
{
    const int idx = blockIdx.x * 256 + threadIdx.x;
    if (idx >= NGIDX) return;
    const int ij = idx / KPAD;
    const int hw = idx - ij * KPAD;
    const int k  = hw_to_klog(hw);
    int off = -1;
    if (k < CIN * KS * KS) {
        const int c = (k >= 98) ? 2 : (k >= 49 ? 1 : 0);
        const int r = k - c * 49;
        const int q = (r * 37) >> 8;
        const int p = r - q * 7;
        const int row  = locs_i[ij * KS + q] - PAD;
        const int colj = locs_j[ij * KS + p] - PAD;
        if ((unsigned)row < (unsigned)IMG && (unsigned)colj < (unsigned)IMG)
            off = c * (IMG * IMG) + row * IMG + colj;
    }
    gidx[idx] = off;
}

// ---------------------------------------------------------------------------
// Conv via MFMA. Block = 4 waves = 4 batches x one 16-position tile.
// 8 consecutive logical blocks cover all 32 batches of a tile; chunked XCD
// swizzle keeps them on one XCD so its L2 serves the tile's gidx slice.
// ---------------------------------------------------------------------------
__global__ __launch_bounds__(256) void foveal_conv_mfma(
    const float* __restrict__ x, const unsigned short* __restrict__ wt,
    const int* __restrict__ gidx, float* __restrict__ out)
{
    const int lane = threadIdx.x & 63;
    const int wid  = threadIdx.x >> 6;

    // chunked XCD swizzle: launched id -> logical id (784 per XCD)
    const int logical = (blockIdx.x & 7) * (NWG / 8) + (blockIdx.x >> 3);
    const int tile    = logical >> 3;       // 0..783  (16-position tile)
    const int bgroup  = logical & 7;        // 0..7
    const int b       = bgroup * 4 + wid;   // batch for this wave
    const int ijbase  = tile * 16;

    const int col = lane & 15;
    const int kb  = (lane >> 4) * 8;

    const int* gp = gidx + (ijbase + col) * KPAD + kb;
    const float* xb = x + (size_t)b * (CIN * IMG * IMG);

    // 1) offset loads: 10x dwordx4, contiguous per lane, L2-shared across waves
    int4 off[5][2];
#pragma unroll
    for (int ks = 0; ks < 5; ++ks) {
        off[ks][0] = *reinterpret_cast<const int4*>(gp + ks * 32);
        off[ks][1] = *reinterpret_cast<const int4*>(gp + ks * 32 + 4);
    }

    // 2) 40 scattered-but-coalesced x loads + pad-select + bf16 pack
    bf16x8 bfrag[5];
#pragma unroll
    for (int ks = 0; ks < 5; ++ks) {
        const int o[8] = { off[ks][0].x, off[ks][0].y, off[ks][0].z, off[ks][0].w,
                           off[ks][1].x, off[ks][1].y, off[ks][1].z, off[ks][1].w };
        float v[8];
#pragma unroll
        for (int e = 0; e < 8; ++e) v[e] = xb[max(o[e], 0)];
#pragma unroll
        for (int e = 0; e < 8; ++e) {
            v[e] = (o[e] < 0) ? 0.5f : v[e];
            bfrag[ks][e] = f2bf(v[e]);
        }
    }

    // 3) MFMA; weight fragments re-loaded per k-step (20 KB, L1-hot)
    f32x4 acc[4];
#pragma unroll
    for (int ct = 0; ct < 4; ++ct) acc[ct] = (f32x4){0.f, 0.f, 0.f, 0.f};

#pragma unroll
    for (int ks = 0; ks < 5; ++ks) {
        bf16x8 afrag[4];
#pragma unroll
        for (int ct = 0; ct < 4; ++ct)
            afrag[ct] = *reinterpret_cast<const bf16x8*>(
                wt + (ct * 16 + col) * KPAD + ks * 32 + kb);
#pragma unroll
        for (int ct = 0; ct < 4; ++ct)
            acc[ct] = __builtin_amdgcn_mfma_f32_16x16x32_bf16(
                afrag[ct], bfrag[ks], acc[ct], 0, 0, 0);
    }

    // 4) store: 16-lane groups write 16 consecutive ij per channel
#pragma unroll
    for (int ct = 0; ct < 4; ++ct) {
#pragma unroll
        for (int r = 0; r < 4; ++r) {
            const int ch = ct * 16 + (lane >> 4) * 4 + r;
            out[((size_t)b * COUT + ch) * PLANE + ijbase + col] = acc[ct][r];
        }
    }
}

// ---------------------------------------------------------------------------
// Pass 2a: per-channel sum / sumsq, float4 reads. One block per (b,o) plane.
// ---------------------------------------------------------------------------
__global__ __launch_bounds__(256) void reduce_stats(
    const float4* __restrict__ out, float* __restrict__ ws)
{
    const int plane = blockIdx.x;           // b*COUT + o
    const int o = plane & (COUT - 1);
    const float4* p = out + (size_t)plane * (PLANE / 4);

    float s = 0.f, sq = 0.f;
    for (int t = threadIdx.x; t < PLANE / 4; t += 256) {
        const float4 v = p[t];
        s  += v.x + v.y + v.z + v.w;
        sq += v.x * v.x + v.y * v.y + v.z * v.z + v.w * v.w;
    }
#pragma unroll
    for (int off = 32; off > 0; off >>= 1) {
        s  += __shfl_down(s,  off);
        sq += __shfl_down(sq, off);
    }
    __shared__ float ls[4], lsq[4];
    const int wid = threadIdx.x >> 6;
    if ((threadIdx.x & 63) == 0) { ls[wid] = s; lsq[wid] = sq; }
    __syncthreads();
    if (threadIdx.x == 0) {
        s  = ls[0] + ls[1] + ls[2] + ls[3];
        sq = lsq[0] + lsq[1] + lsq[2] + lsq[3];
        atomicAdd(&ws[o], s);
        atomicAdd(&ws[COUT + o], sq);
    }
}

__global__ __launch_bounds__(64) void fold_stats(
    float* __restrict__ ws, const float* __restrict__ gamma,
    const float* __restrict__ beta)
{
    const int o = threadIdx.x;
    const float n = (float)NPOS;
    const float mean = ws[o] / n;
    float var = ws[COUT + o] / n - mean * mean;
    var = fmaxf(var, 0.f);
    const float sc = gamma[o] * rsqrtf(var + EPS);
    ws[2 * COUT + o] = sc;
    ws[3 * COUT + o] = beta[o] - mean * sc;
}

__global__ __launch_bounds__(256) void norm_relu(
    float4* __restrict__ out, const float* __restrict__ ws)
{
    const int idx = blockIdx.x * 256 + threadIdx.x;   // < NTOT/4 (exact grid)
    const int o = (idx / (PLANE / 4)) & (COUT - 1);
    const float sc = ws[2 * COUT + o];
    const float sh = ws[3 * COUT + o];
    float4 v = out[idx];
    v.x = fmaxf(fmaf(v.x, sc, sh), 0.f);
    v.y = fmaxf(fmaf(v.y, sc, sh), 0.f);
    v.z = fmaxf(fmaf(v.z, sc, sh), 0.f);
    v.w = fmaxf(fmaf(v.w, sc, sh), 0.f);
    out[idx] = v;
}

// ---------------------------------------------------------------------------
extern "C" void kernel_launch(void* const* d_in, const int* in_sizes, int n_in,
                              void* d_out, int out_size, void* d_ws, size_t ws_size,
                              hipStream_t stream)
{
    const float* x      = (const float*)d_in[0];
    const float* conv_w = (const float*)d_in[1];
    const float* gamma  = (const float*)d_in[2];
    const float* beta   = (const float*)d_in[3];
    const int*   locs_i = (const int*)d_in[4];
    const int*   locs_j = (const int*)d_in[5];
    float* out = (float*)d_out;
    float* ws  = (float*)d_ws;
    unsigned short* wt = (unsigned short*)((char*)d_ws + 1024);       // 20480 B
    int* gidx = (int*)((char*)d_ws + 1024 + 20480);                   // 8 MB

    hipMemsetAsync(d_ws, 0, 1024, stream);  // zero stats area

    prep_weights<<<(COUT * KPAD) / 256, 256, 0, stream>>>(conv_w, wt);
    prep_gidx<<<(NGIDX + 255) / 256, 256, 0, stream>>>(locs_i, locs_j, gidx);
    foveal_conv_mfma<<<NWG, 256, 0, stream>>>(x, wt, gidx, out);
    reduce_stats<<<BATCH * COUT, 256, 0, stream>>>((const float4*)out, ws);
    fold_stats<<<1, 64, 0, stream>>>(ws, gamma, beta);
    norm_relu<<<NTOT / 4 / 256, 256, 0, stream>>>((float4*)out, ws);
}

// Round 6
// 101.197 us; speedup vs baseline: 2.4672x; 2.2297x over previous
//
#include <hip/hip_runtime.h>
#include <hip/hip_bf16.h>

#define L    112
#define IMG  224
#define IMGSQ (IMG * IMG)             // 50176
#define KS   7
#define CIN  3
#define COUT 64
#define BATCH 32
#define PAD  12
#define NPOS (BATCH * L * L)          // 401408
#define PLANE (L * L)                 // 12544
#define NTOT (NPOS * COUT)            // 25690112
#define EPS  1e-5f
#define KPAD 160
#define W    16                       // j-window width = MFMA tile width
#define NJT  (L / W)                  // 7 windows
#define NB   (NJT * BATCH)            // 224 conv blocks
#define MAXBAND 80                    // measured-by-analysis worst band ~70
#define BANDPX (MAXBAND * IMG)        // 17920 px per channel
#define LDSPX (CIN * BANDPX)          // 53760
#define PADSLOT LDSPX                 // sentinel slot, holds bf16(0.5)
#define TILE_U16 (5 * 64 * 8)         // 2560 u16 per tile in offset table
#define NTBL (L * NJT * TILE_U16)     // 784 tiles -> 2007040 u16 (4.01 MB)
#define CONVTH 512                    // 8 waves; each does 14 i-tiles

typedef short bf16x8 __attribute__((ext_vector_type(8)));
typedef float f32x4  __attribute__((ext_vector_type(4)));
typedef unsigned short ushort8 __attribute__((ext_vector_type(8)));

__device__ __forceinline__ short f2bf(float v) {
    __hip_bfloat16 h = __float2bfloat16(v);   // RNE
    return *reinterpret_cast<short*>(&h);
}

// hw slot -> logical k permutation (must match between weights and table).
__device__ __forceinline__ int hw_to_klog(int hw) {
    const int ks  = hw >> 5;
    const int r32 = hw & 31;
    const int kbi = r32 >> 3;
    const int e   = r32 & 7;
    return ks * 32 + e * 4 + kbi;
}

// ---------------------------------------------------------------------------
// Prep A: Wt[o][hw] bf16; k_log = c*49 + q*7 + p -> w[o][c][p][q].
// (row index of gather = locs_i[q], col = locs_j[p]; verified rounds 1-4)
// ---------------------------------------------------------------------------
__global__ __launch_bounds__(256) void prep_weights(
    const float* __restrict__ w, unsigned short* __restrict__ wt)
{
    const int idx = blockIdx.x * 256 + threadIdx.x;   // < COUT*KPAD
    const int o  = idx / KPAD;
    const int hw = idx - o * KPAD;
    const int k  = hw_to_klog(hw);
    float v = 0.f;
    if (k < CIN * KS * KS) {
        const int c = (k >= 98) ? 2 : (k >= 49 ? 1 : 0);
        const int r = k - c * 49;
        const int q = (r * 37) >> 8;          // floor(r/7) for r<49
        const int p = r - q * 7;
        v = w[o * (CIN * KS * KS) + c * (KS * KS) + p * KS + q];
    }
    wt[idx] = (unsigned short)f2bf(v);
}

// ---------------------------------------------------------------------------
// Prep B: per-j-window input row band [lo, lo+nr) from actual lattice rows.
// locs_i flat layout: (i, j, q) -> i*784 + j*7 + q. One block per window.
// ---------------------------------------------------------------------------
__global__ __launch_bounds__(256) void prep_rows(
    const int* __restrict__ locs_i, int* __restrict__ row_lo,
    int* __restrict__ row_nr)
{
    const int jt = blockIdx.x;                // 7 blocks
    int mn = 1 << 30, mx = -(1 << 30);
    for (int t = threadIdx.x; t < L * W * KS; t += 256) {
        const int i  = t / (W * KS);
        const int r  = t - i * (W * KS);
        const int jj = r / KS;
        const int q  = r - jj * KS;
        const int v  = locs_i[i * (L * KS) + (jt * W + jj) * KS + q] - PAD;
        mn = min(mn, v); mx = max(mx, v);
    }
#pragma unroll
    for (int m = 1; m < 64; m <<= 1) {
        mn = min(mn, __shfl_xor(mn, m));
        mx = max(mx, __shfl_xor(mx, m));
    }
    __shared__ int smn[4], smx[4];
    const int wid = threadIdx.x >> 6;
    if ((threadIdx.x & 63) == 0) { smn[wid] = mn; smx[wid] = mx; }
    __syncthreads();
    if (threadIdx.x == 0) {
        mn = min(min(smn[0], smn[1]), min(smn[2], smn[3]));
        mx = max(max(smx[0], smx[1]), max(smx[2], smx[3]));
        row_lo[jt] = max(mn, 0);
        row_nr[jt] = min(mx, IMG - 1) - max(mn, 0) + 1;   // <= MAXBAND
    }
}

// ---------------------------------------------------------------------------
// Prep C: LDS-offset table, conv-load-order layout:
//   tbl[tile][ks][lane][e], tile = jt*112 + i, lane = (kbgrp<<4)|col.
// Value = u16 offset into sband (c*BANDPX + (row-lo)*IMG + colj) or PADSLOT.
// ---------------------------------------------------------------------------
__global__ __launch_bounds__(256) void prep_ldsoff(
    const int* __restrict__ locs_i, const int* __restrict__ locs_j,
    const int* __restrict__ row_lo, unsigned short* __restrict__ tbl)
{
    const int F = blockIdx.x * 256 + threadIdx.x;
    if (F >= NTBL) return;
    const int tile = F / TILE_U16;
    const int r0   = F - tile * TILE_U16;
    const int ks   = r0 >> 9;
    const int r1   = r0 & 511;
    const int lane = r1 >> 3;
    const int e    = r1 & 7;
    const int jt  = tile / L;
    const int i   = tile - jt * L;
    const int col = lane & 15;
    const int kb  = (lane >> 4) * 8;
    const int hw  = ks * 32 + kb + e;
    const int k   = hw_to_klog(hw);
    const int ij  = i * L + jt * W + col;

    unsigned short off = PADSLOT;
    if (k < CIN * KS * KS) {
        const int c = (k >= 98) ? 2 : (k >= 49 ? 1 : 0);
        const int r = k - c * 49;
        const int q = (r * 37) >> 8;
        const int p = r - q * 7;
        const int row  = locs_i[ij * KS + q] - PAD;
        const int colj = locs_j[ij * KS + p] - PAD;
        if ((unsigned)row < (unsigned)IMG && (unsigned)colj < (unsigned)IMG)
            off = (unsigned short)(c * BANDPX + (row - row_lo[jt]) * IMG + colj);
    }
    tbl[F] = off;
}

// ---------------------------------------------------------------------------
// Conv: block = (batch b, j-window jt). Stage row band to LDS (bf16),
// gather via ds_read_u16, MFMA per output row i, fused BN partials.
// ---------------------------------------------------------------------------
__global__ __launch_bounds__(CONVTH) void foveal_conv_mfma(
    const float* __restrict__ x, const unsigned short* __restrict__ wt,
    const unsigned short* __restrict__ tbl,
    const int* __restrict__ row_lo, const int* __restrict__ row_nr,
    float* __restrict__ out, float* __restrict__ partial)
{
    __shared__ unsigned short sband[LDSPX + 8];
    __shared__ float ps[2 * COUT];

    const int tid  = threadIdx.x;
    const int lane = tid & 63;
    const int wv   = tid >> 6;                // 0..7

    // chunked XCD swizzle: 28 consecutive logical blocks per XCD
    const int logical = (blockIdx.x & 7) * (NB / 8) + (blockIdx.x >> 3);
    const int jt = logical >> 5;              // 0..6
    const int b  = logical & 31;

    const int lo = row_lo[jt];
    const int nr = row_nr[jt];

    if (tid < 2 * COUT) ps[tid] = 0.f;
    if (tid == 0) sband[PADSLOT] = 0x3F00;    // bf16(0.5)

    // ---- stage band: 3ch x nr x 224 fp32 -> bf16, coalesced float4 loads
    const float* xb = x + (size_t)b * (CIN * IMGSQ) + lo * IMG;
    const int n4 = nr * (IMG / 4);
#pragma unroll
    for (int c = 0; c < CIN; ++c) {
        const float4* src = reinterpret_cast<const float4*>(xb + c * IMGSQ);
        for (int t = tid; t < n4; t += CONVTH) {
            const float4 v = src[t];
            uint2 uv;
            uv.x = ((unsigned int)(unsigned short)f2bf(v.y) << 16)
                 | (unsigned short)f2bf(v.x);
            uv.y = ((unsigned int)(unsigned short)f2bf(v.w) << 16)
                 | (unsigned short)f2bf(v.z);
            *reinterpret_cast<uint2*>(&sband[c * BANDPX + t * 4]) = uv;
        }
    }
    __syncthreads();

    const int col = lane & 15;
    const int kb  = (lane >> 4) * 8;
    const int g   = lane >> 4;

    // ---- weights: lane-dependent only -> hoist once per wave (L1-hot)
    bf16x8 afrag[4][5];
#pragma unroll
    for (int ct = 0; ct < 4; ++ct)
#pragma unroll
        for (int ks = 0; ks < 5; ++ks)
            afrag[ct][ks] = *reinterpret_cast<const bf16x8*>(
                wt + (ct * 16 + col) * KPAD + ks * 32 + kb);

    // ---- per-lane BN partial accumulators (ch = ct*16 + g*4 + r)
    float ssum[4][4], sqsum[4][4];
#pragma unroll
    for (int ct = 0; ct < 4; ++ct)
#pragma unroll
        for (int r = 0; r < 4; ++r) { ssum[ct][r] = 0.f; sqsum[ct][r] = 0.f; }

    // ---- 14 i-tiles per wave
    for (int tt = 0; tt < L / 8; ++tt) {
        const int i = wv + 8 * tt;
        const int tile = jt * L + i;

        // coalesced table loads: 5 x (1 KB per wave)
        const unsigned short* offp = tbl + (size_t)tile * TILE_U16 + lane * 8;
        bf16x8 bfrag[5];
#pragma unroll
        for (int ks = 0; ks < 5; ++ks) {
            const ushort8 ov = *reinterpret_cast<const ushort8*>(offp + ks * 512);
#pragma unroll
            for (int e = 0; e < 8; ++e)
                bfrag[ks][e] = (short)sband[ov[e]];
        }

        f32x4 acc[4];
#pragma unroll
        for (int ct = 0; ct < 4; ++ct) acc[ct] = (f32x4){0.f, 0.f, 0.f, 0.f};
#pragma unroll
        for (int ks = 0; ks < 5; ++ks)
#pragma unroll
            for (int ct = 0; ct < 4; ++ct)
                acc[ct] = __builtin_amdgcn_mfma_f32_16x16x32_bf16(
                    afrag[ct][ks], bfrag[ks], acc[ct], 0, 0, 0);

        // store (coalesced: 16 consecutive j per 16-lane group) + stats
        float* op = out + (size_t)b * COUT * PLANE + i * L + jt * W + col;
#pragma unroll
        for (int ct = 0; ct < 4; ++ct) {
#pragma unroll
            for (int r = 0; r < 4; ++r) {
                const float v = acc[ct][r];
                op[(size_t)(ct * 16 + g * 4 + r) * PLANE] = v;
                ssum[ct][r]  += v;
                sqsum[ct][r] += v * v;
            }
        }
    }

    // ---- fold per-lane stats: reduce over the 16 cols of each group
#pragma unroll
    for (int ct = 0; ct < 4; ++ct)
#pragma unroll
        for (int r = 0; r < 4; ++r) {
#pragma unroll
            for (int m = 1; m < 16; m <<= 1) {
                ssum[ct][r]  += __shfl_xor(ssum[ct][r],  m);
                sqsum[ct][r] += __shfl_xor(sqsum[ct][r], m);
            }
        }
    if (col == 0) {
#pragma unroll
        for (int ct = 0; ct < 4; ++ct)
#pragma unroll
            for (int r = 0; r < 4; ++r) {
                const int ch = ct * 16 + g * 4 + r;
                atomicAdd(&ps[ch], ssum[ct][r]);
                atomicAdd(&ps[COUT + ch], sqsum[ct][r]);
            }
    }
    __syncthreads();
    if (tid < 2 * COUT) partial[(size_t)blockIdx.x * (2 * COUT) + tid] = ps[tid];
}

// ---------------------------------------------------------------------------
// Fold: per-channel scale/shift from block partials.
// ---------------------------------------------------------------------------
__global__ __launch_bounds__(256) void fold_stats(
    const float* __restrict__ partial, const float* __restrict__ gamma,
    const float* __restrict__ beta, float* __restrict__ wsf)
{
    const int o = blockIdx.x;                 // 64 blocks
    float s = 0.f, sq = 0.f;
    for (int t = threadIdx.x; t < NB; t += 256) {
        s  += partial[(size_t)t * (2 * COUT) + o];
        sq += partial[(size_t)t * (2 * COUT) + COUT + o];
    }
#pragma unroll
    for (int m = 1; m < 64; m <<= 1) {
        s  += __shfl_xor(s, m);
        sq += __shfl_xor(sq, m);
    }
    __shared__ float ls[4], lsq[4];
    const int wid = threadIdx.x >> 6;
    if ((threadIdx.x & 63) == 0) { ls[wid] = s; lsq[wid] = sq; }
    __syncthreads();
    if (threadIdx.x == 0) {
        s  = ls[0] + ls[1] + ls[2] + ls[3];
        sq = lsq[0] + lsq[1] + lsq[2] + lsq[3];
        const float n = (float)NPOS;
        const float mean = s / n;
        float var = sq / n - mean * mean;
        var = fmaxf(var, 0.f);
        const float sc = gamma[o] * rsqrtf(var + EPS);
        wsf[o] = sc;
        wsf[COUT + o] = beta[o] - mean * sc;
    }
}

// ---------------------------------------------------------------------------
// Norm + ReLU, in place, float4.
// ---------------------------------------------------------------------------
__global__ __launch_bounds__(256) void norm_relu(
    float4* __restrict__ out, const float* __restrict__ wsf)
{
    const int idx = blockIdx.x * 256 + threadIdx.x;   // < NTOT/4
    const int o = (idx / (PLANE / 4)) & (COUT - 1);
    const float sc = wsf[o];
    const float sh = wsf[COUT + o];
    float4 v = out[idx];
    v.x = fmaxf(fmaf(v.x, sc, sh), 0.f);
    v.y = fmaxf(fmaf(v.y, sc, sh), 0.f);
    v.z = fmaxf(fmaf(v.z, sc, sh), 0.f);
    v.w = fmaxf(fmaf(v.w, sc, sh), 0.f);
    out[idx] = v;
}

// ---------------------------------------------------------------------------
extern "C" void kernel_launch(void* const* d_in, const int* in_sizes, int n_in,
                              void* d_out, int out_size, void* d_ws, size_t ws_size,
                              hipStream_t stream)
{
    const float* x      = (const float*)d_in[0];
    const float* conv_w = (const float*)d_in[1];
    const float* gamma  = (const float*)d_in[2];
    const float* beta   = (const float*)d_in[3];
    const int*   locs_i = (const int*)d_in[4];
    const int*   locs_j = (const int*)d_in[5];
    float* out = (float*)d_out;

    float* wsf   = (float*)d_ws;                                    // 512 B
    int* row_lo  = (int*)((char*)d_ws + 512);                       // 28 B
    int* row_nr  = (int*)((char*)d_ws + 768);                       // 28 B
    unsigned short* wt = (unsigned short*)((char*)d_ws + 2048);     // 20480 B
    float* partial = (float*)((char*)d_ws + 24576);                 // 114688 B
    unsigned short* tbl =
        (unsigned short*)((char*)d_ws + (2u << 20));                // 4.01 MB

    prep_weights<<<(COUT * KPAD) / 256, 256, 0, stream>>>(conv_w, wt);
    prep_rows<<<NJT, 256, 0, stream>>>(locs_i, row_lo, row_nr);
    prep_ldsoff<<<(NTBL + 255) / 256, 256, 0, stream>>>(
        locs_i, locs_j, row_lo, tbl);
    foveal_conv_mfma<<<NB, CONVTH, 0, stream>>>(
        x, wt, tbl, row_lo, row_nr, out, partial);
    fold_stats<<<COUT, 256, 0, stream>>>(partial, gamma, beta, wsf);
    norm_relu<<<NTOT / 4 / 256, 256, 0, stream>>>((float4*)out, wsf);
}

// Round 7
// 100.678 us; speedup vs baseline: 2.4799x; 1.0052x over previous
//
#include <hip/hip_runtime.h>
#include <hip/hip_bf16.h>

#define L    112
#define IMG  224
#define IMGSQ (IMG * IMG)             // 50176
#define KS   7
#define CIN  3
#define COUT 64
#define BATCH 32
#define PAD  12
#define NPOS (BATCH * L * L)          // 401408
#define PLANE (L * L)                 // 12544
#define NTOT (NPOS * COUT)            // 25690112
#define EPS  1e-5f
#define KPAD 160
#define W    16                       // j-window width = MFMA tile width
#define NJT  (L / W)                  // 7 windows
#define NB   (NJT * BATCH)            // 224 conv blocks
#define MAXBAND 80                    // worst real band ~70 rows (lattice math)
#define BANDPX (MAXBAND * IMG)        // 17920 px per channel
#define LDSPX (CIN * BANDPX)          // 53760
#define PADSLOT LDSPX                 // sentinel slot, holds bf16(0.5)
#define TILE_U16 (5 * 64 * 8)         // 2560 u16 per tile in offset table
#define NTBL (L * NJT * TILE_U16)     // 2007040 u16 (4.01 MB)
#define NLOC (PLANE * KS)             // 87808 locs_i elements
#define CONVTH 512                    // 8 waves; each does 14 i-tiles

typedef short bf16x8 __attribute__((ext_vector_type(8)));
typedef float f32x4  __attribute__((ext_vector_type(4)));
typedef unsigned short ushort8 __attribute__((ext_vector_type(8)));

__device__ __forceinline__ short f2bf(float v) {
    __hip_bfloat16 h = __float2bfloat16(v);   // RNE
    return *reinterpret_cast<short*>(&h);
}

// hw slot -> logical k permutation (must match between weights and table).
__device__ __forceinline__ int hw_to_klog(int hw) {
    const int ks  = hw >> 5;
    const int r32 = hw & 31;
    const int kbi = r32 >> 3;
    const int e   = r32 & 7;
    return ks * 32 + e * 4 + kbi;
}

// ---------------------------------------------------------------------------
// Prep A: Wt[o][hw] bf16; k_log = c*49 + q*7 + p -> w[o][c][p][q].
// ---------------------------------------------------------------------------
__global__ __launch_bounds__(256) void prep_weights(
    const float* __restrict__ w, unsigned short* __restrict__ wt)
{
    const int idx = blockIdx.x * 256 + threadIdx.x;   // < COUT*KPAD
    const int o  = idx / KPAD;
    const int hw = idx - o * KPAD;
    const int k  = hw_to_klog(hw);
    float v = 0.f;
    if (k < CIN * KS * KS) {
        const int c = (k >= 98) ? 2 : (k >= 49 ? 1 : 0);
        const int r = k - c * 49;
        const int q = (r * 37) >> 8;          // floor(r/7) for r<49
        const int p = r - q * 7;
        v = w[o * (CIN * KS * KS) + c * (KS * KS) + p * KS + q];
    }
    wt[idx] = (unsigned short)f2bf(v);
}

// ---------------------------------------------------------------------------
// Prep B: per-j-window row min/max via LDS + global atomics (all CUs busy).
// row_lo pre-initialized to INT_MAX-ish, row_hi to INT_MIN-ish by memset.
// ---------------------------------------------------------------------------
__global__ __launch_bounds__(256) void prep_minmax(
    const int* __restrict__ locs_i, int* __restrict__ row_lo,
    int* __restrict__ row_hi)
{
    __shared__ int lmn[NJT], lmx[NJT];
    if (threadIdx.x < NJT) { lmn[threadIdx.x] = 1 << 30; lmx[threadIdx.x] = -(1 << 30); }
    __syncthreads();
    const int idx = blockIdx.x * 256 + threadIdx.x;
    if (idx < NLOC) {
        const int ij = idx / KS;
        const int jt = (ij % L) >> 4;
        const int v  = locs_i[idx] - PAD;
        atomicMin(&lmn[jt], v);
        atomicMax(&lmx[jt], v);
    }
    __syncthreads();
    if (threadIdx.x < NJT) {
        if (lmn[threadIdx.x] < (1 << 30))  atomicMin(&row_lo[threadIdx.x], lmn[threadIdx.x]);
        if (lmx[threadIdx.x] > -(1 << 30)) atomicMax(&row_hi[threadIdx.x], lmx[threadIdx.x]);
    }
}

// ---------------------------------------------------------------------------
// Prep C: LDS-offset table, conv-load-order layout:
//   tbl[tile][ks][lane][e], tile = jt*112 + i, lane = (kbgrp<<4)|col.
// ---------------------------------------------------------------------------
__global__ __launch_bounds__(256) void prep_ldsoff(
    const int* __restrict__ locs_i, const int* __restrict__ locs_j,
    const int* __restrict__ row_lo, unsigned short* __restrict__ tbl)
{
    const int F = blockIdx.x * 256 + threadIdx.x;
    if (F >= NTBL) return;
    const int tile = F / TILE_U16;
    const int r0   = F - tile * TILE_U16;
    const int ks   = r0 >> 9;
    const int r1   = r0 & 511;
    const int lane = r1 >> 3;
    const int e    = r1 & 7;
    const int jt  = tile / L;
    const int i   = tile - jt * L;
    const int col = lane & 15;
    const int kb  = (lane >> 4) * 8;
    const int hw  = ks * 32 + kb + e;
    const int k   = hw_to_klog(hw);
    const int ij  = i * L + jt * W + col;
    const int lo  = max(row_lo[jt], 0);

    unsigned short off = PADSLOT;
    if (k < CIN * KS * KS) {
        const int c = (k >= 98) ? 2 : (k >= 49 ? 1 : 0);
        const int r = k - c * 49;
        const int q = (r * 37) >> 8;
        const int p = r - q * 7;
        const int row  = locs_i[ij * KS + q] - PAD;
        const int colj = locs_j[ij * KS + p] - PAD;
        if ((unsigned)row < (unsigned)IMG && (unsigned)colj < (unsigned)IMG)
            off = (unsigned short)(c * BANDPX + (row - lo) * IMG + colj);
    }
    tbl[F] = off;
}

// ---------------------------------------------------------------------------
// Conv: block = (batch b, j-window jt). Stage row band to LDS (bf16),
// gather via ds_read_u16, MFMA per output row i, fused BN partials.
// BF16OUT: write bf16 to ws (norm pass reads it); else fp32 to d_out.
// ---------------------------------------------------------------------------
template<bool BF16OUT>
__global__ __launch_bounds__(CONVTH) void foveal_conv_mfma(
    const float* __restrict__ x, const unsigned short* __restrict__ wt,
    const unsigned short* __restrict__ tbl,
    const int* __restrict__ row_lo, const int* __restrict__ row_hi,
    float* __restrict__ out_f32, unsigned short* __restrict__ out_bf16,
    float* __restrict__ partial)
{
    __shared__ unsigned short sband[LDSPX + 8];
    __shared__ float ps[2 * COUT];

    const int tid  = threadIdx.x;
    const int lane = tid & 63;
    const int wv   = tid >> 6;                // 0..7

    // chunked XCD swizzle: 28 consecutive logical blocks per XCD
    const int logical = (blockIdx.x & 7) * (NB / 8) + (blockIdx.x >> 3);
    const int jt = logical >> 5;              // 0..6
    const int b  = logical & 31;

    const int lo = max(row_lo[jt], 0);
    const int nr = min(row_hi[jt], IMG - 1) - lo + 1;

    if (tid < 2 * COUT) ps[tid] = 0.f;
    if (tid == 0) sband[PADSLOT] = 0x3F00;    // bf16(0.5)

    // ---- stage band: 3ch x nr x 224 fp32 -> bf16, coalesced float4 loads
    const float* xb = x + (size_t)b * (CIN * IMGSQ) + lo * IMG;
    const int n4 = nr * (IMG / 4);
#pragma unroll
    for (int c = 0; c < CIN; ++c) {
        const float4* src = reinterpret_cast<const float4*>(xb + c * IMGSQ);
        for (int t = tid; t < n4; t += CONVTH) {
            const float4 v = src[t];
            uint2 uv;
            uv.x = ((unsigned int)(unsigned short)f2bf(v.y) << 16)
                 | (unsigned short)f2bf(v.x);
            uv.y = ((unsigned int)(unsigned short)f2bf(v.w) << 16)
                 | (unsigned short)f2bf(v.z);
            *reinterpret_cast<uint2*>(&sband[c * BANDPX + t * 4]) = uv;
        }
    }
    __syncthreads();

    const int col = lane & 15;
    const int kb  = (lane >> 4) * 8;
    const int g   = lane >> 4;

    // ---- weights: lane-dependent only -> hoist once per wave (L1-hot)
    bf16x8 afrag[4][5];
#pragma unroll
    for (int ct = 0; ct < 4; ++ct)
#pragma unroll
        for (int ks = 0; ks < 5; ++ks)
            afrag[ct][ks] = *reinterpret_cast<const bf16x8*>(
                wt + (ct * 16 + col) * KPAD + ks * 32 + kb);

    // ---- per-lane BN partial accumulators (ch = ct*16 + g*4 + r)
    float ssum[4][4], sqsum[4][4];
#pragma unroll
    for (int ct = 0; ct < 4; ++ct)
#pragma unroll
        for (int r = 0; r < 4; ++r) { ssum[ct][r] = 0.f; sqsum[ct][r] = 0.f; }

    // ---- 14 i-tiles per wave
    for (int tt = 0; tt < L / 8; ++tt) {
        const int i = wv + 8 * tt;
        const int tile = jt * L + i;

        // coalesced table loads: 5 x (1 KB per wave)
        const unsigned short* offp = tbl + (size_t)tile * TILE_U16 + lane * 8;
        bf16x8 bfrag[5];
#pragma unroll
        for (int ks = 0; ks < 5; ++ks) {
            const ushort8 ov = *reinterpret_cast<const ushort8*>(offp + ks * 512);
#pragma unroll
            for (int e = 0; e < 8; ++e)
                bfrag[ks][e] = (short)sband[ov[e]];
        }

        f32x4 acc[4];
#pragma unroll
        for (int ct = 0; ct < 4; ++ct) acc[ct] = (f32x4){0.f, 0.f, 0.f, 0.f};
#pragma unroll
        for (int ks = 0; ks < 5; ++ks)
#pragma unroll
            for (int ct = 0; ct < 4; ++ct)
                acc[ct] = __builtin_amdgcn_mfma_f32_16x16x32_bf16(
                    afrag[ct][ks], bfrag[ks], acc[ct], 0, 0, 0);

        // store (coalesced within 16-lane groups) + stats
        const size_t obase = (size_t)b * COUT * PLANE + i * L + jt * W + col;
#pragma unroll
        for (int ct = 0; ct < 4; ++ct) {
#pragma unroll
            for (int r = 0; r < 4; ++r) {
                const float v = acc[ct][r];
                const size_t oidx = obase + (size_t)(ct * 16 + g * 4 + r) * PLANE;
                if (BF16OUT) out_bf16[oidx] = (unsigned short)f2bf(v);
                else         out_f32[oidx] = v;
                ssum[ct][r]  += v;
                sqsum[ct][r] += v * v;
            }
        }
    }

    // ---- fold per-lane stats: reduce over the 16 cols of each group
#pragma unroll
    for (int ct = 0; ct < 4; ++ct)
#pragma unroll
        for (int r = 0; r < 4; ++r) {
#pragma unroll
            for (int m = 1; m < 16; m <<= 1) {
                ssum[ct][r]  += __shfl_xor(ssum[ct][r],  m);
                sqsum[ct][r] += __shfl_xor(sqsum[ct][r], m);
            }
        }
    if (col == 0) {
#pragma unroll
        for (int ct = 0; ct < 4; ++ct)
#pragma unroll
            for (int r = 0; r < 4; ++r) {
                const int ch = ct * 16 + g * 4 + r;
                atomicAdd(&ps[ch], ssum[ct][r]);
                atomicAdd(&ps[COUT + ch], sqsum[ct][r]);
            }
    }
    __syncthreads();
    if (tid < 2 * COUT) partial[(size_t)blockIdx.x * (2 * COUT) + tid] = ps[tid];
}

// ---------------------------------------------------------------------------
// Fold: per-channel scale/shift from block partials.
// ---------------------------------------------------------------------------
__global__ __launch_bounds__(256) void fold_stats(
    const float* __restrict__ partial, const float* __restrict__ gamma,
    const float* __restrict__ beta, float* __restrict__ wsf)
{
    const int o = blockIdx.x;                 // 64 blocks
    float s = 0.f, sq = 0.f;
    for (int t = threadIdx.x; t < NB; t += 256) {
        s  += partial[(size_t)t * (2 * COUT) + o];
        sq += partial[(size_t)t * (2 * COUT) + COUT + o];
    }
#pragma unroll
    for (int m = 1; m < 64; m <<= 1) {
        s  += __shfl_xor(s, m);
        sq += __shfl_xor(sq, m);
    }
    __shared__ float ls[4], lsq[4];
    const int wid = threadIdx.x >> 6;
    if ((threadIdx.x & 63) == 0) { ls[wid] = s; lsq[wid] = sq; }
    __syncthreads();
    if (threadIdx.x == 0) {
        s  = ls[0] + ls[1] + ls[2] + ls[3];
        sq = lsq[0] + lsq[1] + lsq[2] + lsq[3];
        const float n = (float)NPOS;
        const float mean = s / n;
        float var = sq / n - mean * mean;
        var = fmaxf(var, 0.f);
        const float sc = gamma[o] * rsqrtf(var + EPS);
        wsf[o] = sc;
        wsf[COUT + o] = beta[o] - mean * sc;
    }
}

// ---------------------------------------------------------------------------
// Norm + ReLU. bf16 variant: read ushort8 from ws, write 2x float4 to d_out.
// ---------------------------------------------------------------------------
__global__ __launch_bounds__(256) void norm_relu_bf16(
    const ushort8* __restrict__ in, float4* __restrict__ out,
    const float* __restrict__ wsf)
{
    const int idx = blockIdx.x * 256 + threadIdx.x;   // < NTOT/8
    const int o = (idx / (PLANE / 8)) & (COUT - 1);
    const float sc = wsf[o];
    const float sh = wsf[COUT + o];
    const ushort8 u = in[idx];
    float4 a, c;
    a.x = fmaxf(fmaf(__uint_as_float((unsigned)u[0] << 16), sc, sh), 0.f);
    a.y = fmaxf(fmaf(__uint_as_float((unsigned)u[1] << 16), sc, sh), 0.f);
    a.z = fmaxf(fmaf(__uint_as_float((unsigned)u[2] << 16), sc, sh), 0.f);
    a.w = fmaxf(fmaf(__uint_as_float((unsigned)u[3] << 16), sc, sh), 0.f);
    c.x = fmaxf(fmaf(__uint_as_float((unsigned)u[4] << 16), sc, sh), 0.f);
    c.y = fmaxf(fmaf(__uint_as_float((unsigned)u[5] << 16), sc, sh), 0.f);
    c.z = fmaxf(fmaf(__uint_as_float((unsigned)u[6] << 16), sc, sh), 0.f);
    c.w = fmaxf(fmaf(__uint_as_float((unsigned)u[7] << 16), sc, sh), 0.f);
    out[idx * 2]     = a;
    out[idx * 2 + 1] = c;
}

// fp32 in-place fallback
__global__ __launch_bounds__(256) void norm_relu(
    float4* __restrict__ out, const float* __restrict__ wsf)
{
    const int idx = blockIdx.x * 256 + threadIdx.x;   // < NTOT/4
    const int o = (idx / (PLANE / 4)) & (COUT - 1);
    const float sc = wsf[o];
    const float sh = wsf[COUT + o];
    float4 v = out[idx];
    v.x = fmaxf(fmaf(v.x, sc, sh), 0.f);
    v.y = fmaxf(fmaf(v.y, sc, sh), 0.f);
    v.z = fmaxf(fmaf(v.z, sc, sh), 0.f);
    v.w = fmaxf(fmaf(v.w, sc, sh), 0.f);
    out[idx] = v;
}

// ---------------------------------------------------------------------------
extern "C" void kernel_launch(void* const* d_in, const int* in_sizes, int n_in,
                              void* d_out, int out_size, void* d_ws, size_t ws_size,
                              hipStream_t stream)
{
    const float* x      = (const float*)d_in[0];
    const float* conv_w = (const float*)d_in[1];
    const float* gamma  = (const float*)d_in[2];
    const float* beta   = (const float*)d_in[3];
    const int*   locs_i = (const int*)d_in[4];
    const int*   locs_j = (const int*)d_in[5];
    float* out = (float*)d_out;

    float* wsf   = (float*)d_ws;                                    // 512 B
    int* row_lo  = (int*)((char*)d_ws + 512);                       // 28 B
    int* row_hi  = (int*)((char*)d_ws + 768);                       // 28 B
    unsigned short* wt = (unsigned short*)((char*)d_ws + 2048);     // 20480 B
    float* partial = (float*)((char*)d_ws + 32768);                 // 114688 B
    unsigned short* tbl =
        (unsigned short*)((char*)d_ws + (1u << 20));                // 4.01 MB
    unsigned short* cbf =
        (unsigned short*)((char*)d_ws + (6u << 20));                // 51.4 MB

    const bool use_bf16 = ws_size >= (size_t)(6u << 20) + (size_t)NTOT * 2;

    hipMemsetAsync(row_lo, 0x7F, NJT * sizeof(int), stream);        // +big
    hipMemsetAsync(row_hi, 0x80, NJT * sizeof(int), stream);        // -big

    prep_weights<<<(COUT * KPAD) / 256, 256, 0, stream>>>(conv_w, wt);
    prep_minmax<<<(NLOC + 255) / 256, 256, 0, stream>>>(locs_i, row_lo, row_hi);
    prep_ldsoff<<<(NTBL + 255) / 256, 256, 0, stream>>>(
        locs_i, locs_j, row_lo, tbl);
    if (use_bf16) {
        foveal_conv_mfma<true><<<NB, CONVTH, 0, stream>>>(
            x, wt, tbl, row_lo, row_hi, out, cbf, partial);
        fold_stats<<<COUT, 256, 0, stream>>>(partial, gamma, beta, wsf);
        norm_relu_bf16<<<NTOT / 8 / 256, 256, 0, stream>>>(
            (const ushort8*)cbf, (float4*)out, wsf);
    } else {
        foveal_conv_mfma<false><<<NB, CONVTH, 0, stream>>>(
            x, wt, tbl, row_lo, row_hi, out, cbf, partial);
        fold_stats<<<COUT, 256, 0, stream>>>(partial, gamma, beta, wsf);
        norm_relu<<<NTOT / 4 / 256, 256, 0, stream>>>((float4*)out, wsf);
    }
}